// Round 5
// baseline (253.888 us; speedup 1.0000x reference)
//
#include <hip/hip_runtime.h>
#include <hip/hip_bf16.h>
#include <stdint.h>

// MultiHeadAttention (buggy-transpose variant), MI355X/gfx950.
// R5: barrier-free K-loop GEMMs. B (weights) staged to LDS once per K-half
// (64KB, XOR-swizzled); A loaded straight to VGPRs in MFMA fragment layout
// with explicit ping-pong batch-of-4 prefetch (forces 8 outstanding 1KB
// loads/wave -- the MLP the compiler refused to create in R2/R3).
//
// Pipeline:
//   k0 wtrans: Wq,Wk,Wv,Wp fp32 [K][N] -> bf16 W^T [N][K] in ws
//   k1 qkv:    [q|k|v] @ W + b -> fp32 qkv   (16384x64x1024 per proj)
//   k2 group:  KV[b][a]=0.25*sum_j k[b,j]v[a,j]; X[n,64a+i]=sum_b q[b,i]KV[b][a]
//              (mask all-ones, softmax computed-then-discarded -> linear)
//   k3 out:    X @ Wp + bp   (1024^3 bf16 MFMA)

typedef float f32x4 __attribute__((ext_vector_type(4)));
typedef short s16x8 __attribute__((ext_vector_type(8)));

#define T_TOK 16384
#define KDIM  1024
#define HS    64

__device__ __forceinline__ short f2bf(float f) {
    union { float f; uint32_t u; } x; x.f = f;
    uint32_t u = x.u;
    u += 0x7FFFu + ((u >> 16) & 1u);   // round-to-nearest-even
    return (short)(u >> 16);
}

// ---------------- Kernel 0: weight transpose+cvt  fp32 [K][N] -> bf16 [N][K] ----
__global__ __launch_bounds__(256) void wtrans_kernel(
    const float* __restrict__ Wq, const float* __restrict__ Wk,
    const float* __restrict__ Wv, const float* __restrict__ Wp,
    short* __restrict__ Wtq, short* __restrict__ Wtk,
    short* __restrict__ Wtv, short* __restrict__ Wpt)
{
    const int bid = blockIdx.x;
    const float* src; short* dst; int N, k0, n0;
    if (bid < 256) { src = Wp; dst = Wpt; N = 1024; k0 = (bid >> 4) * 64; n0 = (bid & 15) * 64; }
    else {
        int r = bid - 256; int p = r >> 4;
        src = (p == 0) ? Wq : (p == 1) ? Wk : Wv;
        dst = (p == 0) ? Wtq : (p == 1) ? Wtk : Wtv;
        N = 64; k0 = (r & 15) * 64; n0 = 0;
    }
    __shared__ float Ts[64][68];
    const int tid = threadIdx.x;
    #pragma unroll
    for (int i = 0; i < 4; ++i) {
        int idx = i * 256 + tid;
        int r = idx >> 4, c4 = idx & 15;
        f32x4 v = *(const f32x4*)&src[(size_t)(k0 + r) * N + n0 + c4 * 4];
        *(f32x4*)&Ts[r][c4 * 4] = v;
    }
    __syncthreads();
    #pragma unroll
    for (int i = 0; i < 2; ++i) {
        int idx = i * 256 + tid;
        int n = idx >> 3, c8 = idx & 7;
        s16x8 h;
        #pragma unroll
        for (int j = 0; j < 8; ++j) h[j] = f2bf(Ts[c8 * 8 + j][n]);
        *(s16x8*)&dst[(size_t)(n0 + n) * KDIM + k0 + c8 * 8] = h;
    }
}

// ---------------- Kernel 1: fused QKV projection ----------------
// grid (256, 3), block 256 (4 waves). Block: 64 tokens x all 64 n.
// B (64 x 512 bf16 = 64KB) staged per K-half; A direct-to-VGPR ping-pong.
__global__ __launch_bounds__(256, 2) void qkv_proj_kernel(
    const float* __restrict__ Q, const float* __restrict__ K,
    const float* __restrict__ V,
    const short* __restrict__ Wtq, const short* __restrict__ Wtk,
    const short* __restrict__ Wtv,
    const float* __restrict__ bq, const float* __restrict__ bk,
    const float* __restrict__ bv,
    float* __restrict__ OutQKV)
{
    const int p = blockIdx.y;
    const float* In = (p == 0) ? Q : (p == 1) ? K : V;
    const short* Wt = (p == 0) ? Wtq : (p == 1) ? Wtk : Wtv;
    const float* bb = (p == 0) ? bq : (p == 1) ? bk : bv;
    float* Out = OutQKV + (size_t)p * T_TOK * HS;

    __shared__ short Bs[64 * 512];   // 64KB: [n 0..63][k-half 512], granule16 XOR swizzle

    const int tid  = threadIdx.x;
    const int wave = tid >> 6;
    const int lane = tid & 63;
    const int lhi  = lane >> 4;   // 0..3
    const int llo  = lane & 15;
    const int t0   = blockIdx.x * 64;

    const float* ap_base = In + (size_t)(t0 + wave * 16 + llo) * KDIM + lhi * 8;

    f32x4 acc[4] = {};

    for (int kh = 0; kh < 2; ++kh) {
        __syncthreads();   // previous half's readers done (no-op on first pass)
        #pragma unroll
        for (int i = 0; i < 16; ++i) {   // stage B half: 4096 x s16x8
            int G = i * 256 + tid;
            int r = G >> 6, g = G & 63;
            s16x8 w = *(const s16x8*)&Wt[(size_t)r * KDIM + kh * 512 + g * 8];
            *(s16x8*)&Bs[r * 512 + (g ^ (r & 7)) * 8] = w;
        }
        __syncthreads();

        const float* ap = ap_base + kh * 512;
        f32x4 abuf[2][4][2];
        #pragma unroll
        for (int c = 0; c < 4; ++c) {
            abuf[0][c][0] = *(const f32x4*)(ap + c * 32);
            abuf[0][c][1] = *(const f32x4*)(ap + c * 32 + 4);
        }
        for (int o = 0; o < 4; ++o) {
            const int pp = o & 1;
            if (o < 3) {
                const float* apn = ap + (o + 1) * 128;
                #pragma unroll
                for (int c = 0; c < 4; ++c) {
                    abuf[pp ^ 1][c][0] = *(const f32x4*)(apn + c * 32);
                    abuf[pp ^ 1][c][1] = *(const f32x4*)(apn + c * 32 + 4);
                }
            }
            #pragma unroll
            for (int c = 0; c < 4; ++c) {
                f32x4 a0 = abuf[pp][c][0], a1 = abuf[pp][c][1];
                s16x8 af;
                af[0] = f2bf(a0.x); af[1] = f2bf(a0.y); af[2] = f2bf(a0.z); af[3] = f2bf(a0.w);
                af[4] = f2bf(a1.x); af[5] = f2bf(a1.y); af[6] = f2bf(a1.z); af[7] = f2bf(a1.w);
                const int gk = o * 16 + c * 4 + lhi;   // granule 0..63
                #pragma unroll
                for (int nt = 0; nt < 4; ++nt) {
                    int n = nt * 16 + llo;
                    s16x8 bf = *(const s16x8*)&Bs[n * 512 + (gk ^ (n & 7)) * 8];
                    acc[nt] = __builtin_amdgcn_mfma_f32_16x16x32_bf16(af, bf, acc[nt], 0, 0, 0);
                }
            }
        }
    }

    // D layout: row = lhi*4 + r (token), col = llo (n within tile)
    #pragma unroll
    for (int nt = 0; nt < 4; ++nt) {
        const int col = nt * 16 + llo;
        const float bias = bb[col];
        #pragma unroll
        for (int r = 0; r < 4; ++r)
            Out[(size_t)(t0 + wave * 16 + lhi * 4 + r) * HS + col] = acc[nt][r] + bias;
    }
}

// ---------------- Kernel 2: grouped "attention" (linear, KV trick) ----------------
__global__ __launch_bounds__(256) void group_attn_kernel(
    const float* __restrict__ QKV, short* __restrict__ Xbf)
{
    const int n = blockIdx.x;
    __shared__ float Sq[16][68];
    __shared__ float Sk[16][68];
    __shared__ float Sv[16][68];
    __shared__ float KV[16][17];

    const int tid = threadIdx.x;
    const float* qp = QKV + (size_t)n * 16 * HS;
    const float* kp = qp + (size_t)T_TOK * HS;
    const float* vp = kp + (size_t)T_TOK * HS;

    {   // vectorized loads: 256 threads x f32x4 = 1024 floats per matrix
        int row = tid >> 4, c4 = (tid & 15) * 4;
        *(f32x4*)&Sq[row][c4] = *(const f32x4*)&qp[tid * 4];
        *(f32x4*)&Sk[row][c4] = *(const f32x4*)&kp[tid * 4];
        *(f32x4*)&Sv[row][c4] = *(const f32x4*)&vp[tid * 4];
    }
    __syncthreads();

    {   // KV[b][a] = 0.25 * sum_j Sk[b][j]*Sv[a][j]
        int b = tid >> 4, a = tid & 15;
        const f32x4* kb = (const f32x4*)&Sk[b][0];
        const f32x4* va = (const f32x4*)&Sv[a][0];
        float s = 0.f;
        #pragma unroll
        for (int j = 0; j < 16; ++j) {
            f32x4 x = kb[j], y = va[j];
            s += x.x * y.x + x.y * y.y + x.z * y.z + x.w * y.w;
        }
        KV[b][a] = s * 0.25f;
    }
    __syncthreads();

    const int i = tid & 63;
    const int w = tid >> 6;
    float qv[16];
    #pragma unroll
    for (int b = 0; b < 16; ++b) qv[b] = Sq[b][i];
    #pragma unroll
    for (int u = 0; u < 4; ++u) {
        int a = u * 4 + w;
        float s = 0.f;
        #pragma unroll
        for (int b = 0; b < 16; ++b) s += qv[b] * KV[b][a];
        Xbf[(size_t)n * 1024 + a * 64 + i] = f2bf(s);
    }
}

// ---------------- Kernel 3: out = X @ Wp + bp (1024^3) ----------------
// grid (16, 16), block 256. Block: 64 m x 64 n; B half-K in LDS; A direct bf16.
__global__ __launch_bounds__(256, 2) void out_proj_kernel(
    const short* __restrict__ Xbf, const short* __restrict__ Wpt,
    const float* __restrict__ bp, float* __restrict__ Out)
{
    __shared__ short Bs[64 * 512];   // 64KB

    const int tid  = threadIdx.x;
    const int wave = tid >> 6;
    const int lane = tid & 63;
    const int lhi  = lane >> 4, llo = lane & 15;
    const int m0   = blockIdx.x * 64;
    const int n0   = blockIdx.y * 64;

    const short* ap_base = Xbf + (size_t)(m0 + wave * 16 + llo) * KDIM + lhi * 8;

    f32x4 acc[4] = {};

    for (int kh = 0; kh < 2; ++kh) {
        __syncthreads();
        #pragma unroll
        for (int i = 0; i < 16; ++i) {
            int G = i * 256 + tid;
            int r = G >> 6, g = G & 63;
            s16x8 w = *(const s16x8*)&Wpt[(size_t)(n0 + r) * KDIM + kh * 512 + g * 8];
            *(s16x8*)&Bs[r * 512 + (g ^ (r & 7)) * 8] = w;
        }
        __syncthreads();

        const short* ap = ap_base + kh * 512;
        s16x8 abuf[2][4];
        #pragma unroll
        for (int c = 0; c < 4; ++c) abuf[0][c] = *(const s16x8*)(ap + c * 32);
        for (int o = 0; o < 4; ++o) {
            const int pp = o & 1;
            if (o < 3) {
                const short* apn = ap + (o + 1) * 128;
                #pragma unroll
                for (int c = 0; c < 4; ++c) abuf[pp ^ 1][c] = *(const s16x8*)(apn + c * 32);
            }
            #pragma unroll
            for (int c = 0; c < 4; ++c) {
                const int gk = o * 16 + c * 4 + lhi;
                #pragma unroll
                for (int nt = 0; nt < 4; ++nt) {
                    int n = nt * 16 + llo;
                    s16x8 bf = *(const s16x8*)&Bs[n * 512 + (gk ^ (n & 7)) * 8];
                    acc[nt] = __builtin_amdgcn_mfma_f32_16x16x32_bf16(abuf[pp][c], bf, acc[nt], 0, 0, 0);
                }
            }
        }
    }

    #pragma unroll
    for (int nt = 0; nt < 4; ++nt) {
        const int col = n0 + nt * 16 + llo;
        const float bias = bp[col];
        #pragma unroll
        for (int r = 0; r < 4; ++r)
            Out[(size_t)(m0 + wave * 16 + lhi * 4 + r) * KDIM + col] = acc[nt][r] + bias;
    }
}

extern "C" void kernel_launch(void* const* d_in, const int* in_sizes, int n_in,
                              void* d_out, int out_size, void* d_ws, size_t ws_size,
                              hipStream_t stream) {
    const float* Q  = (const float*)d_in[0];
    const float* K  = (const float*)d_in[1];
    const float* V  = (const float*)d_in[2];
    // d_in[3] = mask: all ones -> identity (enables linearization)
    const float* Wq = (const float*)d_in[4];
    const float* bq = (const float*)d_in[5];
    const float* Wk = (const float*)d_in[6];
    const float* bk = (const float*)d_in[7];
    const float* Wv = (const float*)d_in[8];
    const float* bv = (const float*)d_in[9];
    const float* Wp = (const float*)d_in[10];
    const float* bp = (const float*)d_in[11];
    float* out = (float*)d_out;

    char* ws = (char*)d_ws;
    float* qkv = (float*)ws;                              // 3*16384*64 fp32 = 12.58 MB
    size_t off = (size_t)3 * T_TOK * HS * sizeof(float);
    short* Xbf = (short*)(ws + off); off += (size_t)1024 * 1024 * 2;   // 2 MB
    short* Wtq = (short*)(ws + off); off += (size_t)HS * KDIM * 2;     // 128 KB
    short* Wtk = (short*)(ws + off); off += (size_t)HS * KDIM * 2;
    short* Wtv = (short*)(ws + off); off += (size_t)HS * KDIM * 2;
    short* Wpt = (short*)(ws + off); off += (size_t)KDIM * KDIM * 2;   // 2 MB

    wtrans_kernel<<<dim3(304), 256, 0, stream>>>(Wq, Wk, Wv, Wp, Wtq, Wtk, Wtv, Wpt);
    qkv_proj_kernel<<<dim3(T_TOK / 64, 3), 256, 0, stream>>>(
        Q, K, V, Wtq, Wtk, Wtv, bq, bk, bv, qkv);
    group_attn_kernel<<<dim3(1024), 256, 0, stream>>>(qkv, Xbf);
    out_proj_kernel<<<dim3(16, 16), 256, 0, stream>>>(Xbf, Wpt, bp, out);
}

// Round 6
// 250.291 us; speedup vs baseline: 1.0144x; 1.0144x over previous
//
#include <hip/hip_runtime.h>
#include <hip/hip_bf16.h>
#include <stdint.h>

// MultiHeadAttention (buggy-transpose variant), MI355X/gfx950.
// R6: wave-private async pipelines. Each wave stages its A-chunks into its OWN
// LDS ring (4 slots) via global_load_lds and gates consumption with manual
// `s_waitcnt vmcnt(N)` (per-wave counter, issue-order semantics) -- no
// __syncthreads anywhere in the K-loop, 12KB+ per wave permanently in flight.
// B (weight slice) in 128 AGPRs per wave. Compiler cannot collapse this
// pipeline (intrinsic DMA + asm memory barriers pin the schedule).
//
// Pipeline:
//   k0 wtrans: Wq,Wk,Wv,Wp fp32 [K][N] -> bf16 W^T [N][K] in ws
//   k1 qkv:    [q|k|v] @ W + b -> fp32 qkv   (16384x64x1024 per proj)
//   k2 group:  KV[b][a]=0.25*sum_j k[b,j]v[a,j]; X[n,64a+i]=sum_b q[b,i]KV[b][a]
//              (mask all-ones, softmax computed-then-discarded -> linear)
//   k3 out:    X @ Wp + bp   (1024^3 bf16 MFMA), same wave-private structure

typedef float f32x4 __attribute__((ext_vector_type(4)));
typedef short s16x8 __attribute__((ext_vector_type(8)));

#define T_TOK 16384
#define KDIM  1024
#define HS    64

__device__ __forceinline__ short f2bf(float f) {
    union { float f; uint32_t u; } x; x.f = f;
    uint32_t u = x.u;
    u += 0x7FFFu + ((u >> 16) & 1u);   // round-to-nearest-even
    return (short)(u >> 16);
}

__device__ __forceinline__ void gl2lds16(const void* g, void* l) {
    __builtin_amdgcn_global_load_lds(
        (const __attribute__((address_space(1))) void*)g,
        (__attribute__((address_space(3))) void*)l, 16, 0, 0);
}

// compile-time-selected wait: keep >=N vm-ops outstanding resolved
__device__ __forceinline__ void wait_vm(int n) {
    if (n >= 12)      asm volatile("s_waitcnt vmcnt(12)" ::: "memory");
    else if (n == 8)  asm volatile("s_waitcnt vmcnt(8)"  ::: "memory");
    else if (n == 6)  asm volatile("s_waitcnt vmcnt(6)"  ::: "memory");
    else if (n == 4)  asm volatile("s_waitcnt vmcnt(4)"  ::: "memory");
    else if (n == 2)  asm volatile("s_waitcnt vmcnt(2)"  ::: "memory");
    else              asm volatile("s_waitcnt vmcnt(0)"  ::: "memory");
}

// ---------------- Kernel 0: weight transpose+cvt  fp32 [K][N] -> bf16 [N][K] ----
__global__ __launch_bounds__(256) void wtrans_kernel(
    const float* __restrict__ Wq, const float* __restrict__ Wk,
    const float* __restrict__ Wv, const float* __restrict__ Wp,
    short* __restrict__ Wtq, short* __restrict__ Wtk,
    short* __restrict__ Wtv, short* __restrict__ Wpt)
{
    const int bid = blockIdx.x;
    const float* src; short* dst; int N, k0, n0;
    if (bid < 256) { src = Wp; dst = Wpt; N = 1024; k0 = (bid >> 4) * 64; n0 = (bid & 15) * 64; }
    else {
        int r = bid - 256; int p = r >> 4;
        src = (p == 0) ? Wq : (p == 1) ? Wk : Wv;
        dst = (p == 0) ? Wtq : (p == 1) ? Wtk : Wtv;
        N = 64; k0 = (r & 15) * 64; n0 = 0;
    }
    __shared__ float Ts[64][68];
    const int tid = threadIdx.x;
    #pragma unroll
    for (int i = 0; i < 4; ++i) {
        int idx = i * 256 + tid;
        int r = idx >> 4, c4 = idx & 15;
        f32x4 v = *(const f32x4*)&src[(size_t)(k0 + r) * N + n0 + c4 * 4];
        *(f32x4*)&Ts[r][c4 * 4] = v;
    }
    __syncthreads();
    #pragma unroll
    for (int i = 0; i < 2; ++i) {
        int idx = i * 256 + tid;
        int n = idx >> 3, c8 = idx & 7;
        s16x8 h;
        #pragma unroll
        for (int j = 0; j < 8; ++j) h[j] = f2bf(Ts[c8 * 8 + j][n]);
        *(s16x8*)&dst[(size_t)(n0 + n) * KDIM + k0 + c8 * 8] = h;
    }
}

// ---------------- Kernel 1: fused QKV projection, wave-private async pipeline ----
// grid (256, 3), block 256 (4 waves). Block -> 64 tokens (4 tiles of 16, sequential
// per wave); wave w -> n-slice [16w,16w+16), full K in 128 AGPRs.
// Chunk = 16 tokens x 64 fp32 = 4KB = 4x global_load_lds(16B); ring of 4 chunks.
__global__ __launch_bounds__(256, 2) void qkv_proj_kernel(
    const float* __restrict__ Q, const float* __restrict__ K,
    const float* __restrict__ V,
    const short* __restrict__ Wtq, const short* __restrict__ Wtk,
    const short* __restrict__ Wtv,
    const float* __restrict__ bq, const float* __restrict__ bk,
    const float* __restrict__ bv,
    float* __restrict__ OutQKV)
{
    const int p = blockIdx.y;
    const float* In = (p == 0) ? Q : (p == 1) ? K : V;
    const short* Wt = (p == 0) ? Wtq : (p == 1) ? Wtk : Wtv;
    const float* bb = (p == 0) ? bq : (p == 1) ? bk : bv;
    float* Out = OutQKV + (size_t)p * T_TOK * HS;

    __shared__ __align__(16) char lds[4][16384];   // [wave][4 slots x 4KB]

    const int tid  = threadIdx.x;
    const int wave = tid >> 6;
    const int lane = tid & 63;
    const int lhi  = lane >> 4;   // 0..3
    const int llo  = lane & 15;
    const int t0   = blockIdx.x * 64;
    const int n0   = wave * 16;
    char* ldsw = &lds[wave][0];

    // B: wave's n-slice x full K in registers (32 x s16x8 = 128 regs -> AGPR)
    s16x8 breg[32];
    const short* wp = Wt + (size_t)(n0 + llo) * KDIM + lhi * 8;
    #pragma unroll
    for (int i = 0; i < 32; ++i) breg[i] = *(const s16x8*)(wp + i * 32);
    const float bias = bb[n0 + llo];

    // staging source offsets (per lane, per inst j): row r_j = j*4 + lane>>4,
    // stored granule32 p32 = (lane&15)>>1, data granule = p32 ^ (r_j&7), half = lane&1
    int aoff[4];
    #pragma unroll
    for (int j = 0; j < 4; ++j) {
        int rj = j * 4 + (lane >> 4);
        aoff[j] = rj * KDIM + ((((lane & 15) >> 1) ^ (rj & 7)) * 8 + (lane & 1) * 4);
    }
    const int ldst = lane * 16;

    #define ISSUE_Q(u) do {                                                     \
        const float* _b = In + (size_t)t0 * KDIM                                \
                          + ((u) >> 4) * 16 * KDIM + ((u) & 15) * 64;           \
        char* _d = ldsw + ((u) & 3) * 4096;                                     \
        gl2lds16(_b + aoff[0], _d + 0 * 1024 + ldst);                           \
        gl2lds16(_b + aoff[1], _d + 1 * 1024 + ldst);                           \
        gl2lds16(_b + aoff[2], _d + 2 * 1024 + ldst);                           \
        gl2lds16(_b + aoff[3], _d + 3 * 1024 + ldst);                           \
    } while (0)

    ISSUE_Q(0); ISSUE_Q(1); ISSUE_Q(2); ISSUE_Q(3);

    f32x4 acc = {};
    #pragma unroll
    for (int u = 0; u < 64; ++u) {
        wait_vm(u <= 60 ? 12 : (63 - u) * 4);   // chunk u resolved (issue-order vmcnt)
        const char* slot = ldsw + (u & 3) * 4096;
        #pragma unroll
        for (int s = 0; s < 2; ++s) {
            int pos = (s * 4 + lhi) ^ (llo & 7);
            const f32x4* ap = (const f32x4*)(slot + llo * 256 + pos * 32);
            f32x4 a0 = ap[0], a1 = ap[1];
            s16x8 af;
            af[0] = f2bf(a0.x); af[1] = f2bf(a0.y); af[2] = f2bf(a0.z); af[3] = f2bf(a0.w);
            af[4] = f2bf(a1.x); af[5] = f2bf(a1.y); af[6] = f2bf(a1.z); af[7] = f2bf(a1.w);
            acc = __builtin_amdgcn_mfma_f32_16x16x32_bf16(af, breg[(u & 15) * 2 + s], acc, 0, 0, 0);
        }
        if (u + 4 < 64) ISSUE_Q(u + 4);
        if ((u & 15) == 15) {   // tile (u>>4) complete: write 16x16
            const int row0 = t0 + (u >> 4) * 16 + lhi * 4;
            #pragma unroll
            for (int r = 0; r < 4; ++r)
                Out[(size_t)(row0 + r) * HS + n0 + llo] = acc[r] + bias;
            acc = (f32x4){};
        }
    }
    #undef ISSUE_Q
}

// ---------------- Kernel 2: grouped "attention" (linear, KV trick) ----------------
__global__ __launch_bounds__(256) void group_attn_kernel(
    const float* __restrict__ QKV, short* __restrict__ Xbf)
{
    const int n = blockIdx.x;
    __shared__ float Sq[16][68];
    __shared__ float Sk[16][68];
    __shared__ float Sv[16][68];
    __shared__ float KV[16][17];

    const int tid = threadIdx.x;
    const float* qp = QKV + (size_t)n * 16 * HS;
    const float* kp = qp + (size_t)T_TOK * HS;
    const float* vp = kp + (size_t)T_TOK * HS;

    {   // vectorized loads: 256 threads x f32x4 = 1024 floats per matrix
        int row = tid >> 4, c4 = (tid & 15) * 4;
        *(f32x4*)&Sq[row][c4] = *(const f32x4*)&qp[tid * 4];
        *(f32x4*)&Sk[row][c4] = *(const f32x4*)&kp[tid * 4];
        *(f32x4*)&Sv[row][c4] = *(const f32x4*)&vp[tid * 4];
    }
    __syncthreads();

    {   // KV[b][a] = 0.25 * sum_j Sk[b][j]*Sv[a][j]
        int b = tid >> 4, a = tid & 15;
        const f32x4* kb = (const f32x4*)&Sk[b][0];
        const f32x4* va = (const f32x4*)&Sv[a][0];
        float s = 0.f;
        #pragma unroll
        for (int j = 0; j < 16; ++j) {
            f32x4 x = kb[j], y = va[j];
            s += x.x * y.x + x.y * y.y + x.z * y.z + x.w * y.w;
        }
        KV[b][a] = s * 0.25f;
    }
    __syncthreads();

    const int i = tid & 63;
    const int w = tid >> 6;
    float qv[16];
    #pragma unroll
    for (int b = 0; b < 16; ++b) qv[b] = Sq[b][i];
    #pragma unroll
    for (int u = 0; u < 4; ++u) {
        int a = u * 4 + w;
        float s = 0.f;
        #pragma unroll
        for (int b = 0; b < 16; ++b) s += qv[b] * KV[b][a];
        Xbf[(size_t)n * 1024 + a * 64 + i] = f2bf(s);
    }
}

// ---------------- Kernel 3: out = X @ Wp + bp, wave-private async pipeline ----
// grid (16 n-groups, 32 m-groups), block 256. Wave: n-slice 16 (B in 128 AGPRs),
// m-range 32 rows = 2 tiles x 16 k-chunks. Chunk = 16 rows x 64 bf16 = 2KB (2 insts).
__global__ __launch_bounds__(256, 2) void out_proj_kernel(
    const short* __restrict__ Xbf, const short* __restrict__ Wpt,
    const float* __restrict__ bp, float* __restrict__ Out)
{
    __shared__ __align__(16) char lds[4][8192];   // [wave][4 slots x 2KB]

    const int tid  = threadIdx.x;
    const int wave = tid >> 6;
    const int lane = tid & 63;
    const int lhi  = lane >> 4, llo = lane & 15;
    const int n0   = blockIdx.x * 64 + wave * 16;
    const int m0   = blockIdx.y * 32;
    char* ldsw = &lds[wave][0];

    s16x8 breg[32];
    const short* wp = Wpt + (size_t)(n0 + llo) * KDIM + lhi * 8;
    #pragma unroll
    for (int i = 0; i < 32; ++i) breg[i] = *(const s16x8*)(wp + i * 32);
    const float bias = bp[n0 + llo];

    // staging: inst j (0,1): row r_j = j*8 + lane>>3, granule q = lane&7,
    // source granule = q ^ (r_j&7)
    int aoff[2];
    #pragma unroll
    for (int j = 0; j < 2; ++j) {
        int rj = j * 8 + (lane >> 3);
        aoff[j] = rj * KDIM + ((lane & 7) ^ (rj & 7)) * 8;
    }
    const int ldst = lane * 16;

    #define ISSUE_O(u) do {                                                     \
        const short* _b = Xbf + (size_t)m0 * KDIM                               \
                          + ((u) >> 4) * 16 * KDIM + ((u) & 15) * 64;           \
        char* _d = ldsw + ((u) & 3) * 2048;                                     \
        gl2lds16(_b + aoff[0], _d + 0 * 1024 + ldst);                           \
        gl2lds16(_b + aoff[1], _d + 1 * 1024 + ldst);                           \
    } while (0)

    ISSUE_O(0); ISSUE_O(1); ISSUE_O(2); ISSUE_O(3);

    f32x4 acc = {};
    #pragma unroll
    for (int u = 0; u < 32; ++u) {
        wait_vm(u <= 28 ? 6 : (31 - u) * 2);
        const char* slot = ldsw + (u & 3) * 2048;
        #pragma unroll
        for (int s = 0; s < 2; ++s) {
            int pos = (s * 4 + lhi) ^ (llo & 7);
            s16x8 af = *(const s16x8*)(slot + llo * 128 + pos * 16);
            acc = __builtin_amdgcn_mfma_f32_16x16x32_bf16(af, breg[(u & 15) * 2 + s], acc, 0, 0, 0);
        }
        if (u + 4 < 32) ISSUE_O(u + 4);
        if ((u & 15) == 15) {
            const int row0 = m0 + (u >> 4) * 16 + lhi * 4;
            #pragma unroll
            for (int r = 0; r < 4; ++r)
                Out[(size_t)(row0 + r) * KDIM + n0 + llo] = acc[r] + bias;
            acc = (f32x4){};
        }
    }
    #undef ISSUE_O
}

extern "C" void kernel_launch(void* const* d_in, const int* in_sizes, int n_in,
                              void* d_out, int out_size, void* d_ws, size_t ws_size,
                              hipStream_t stream) {
    const float* Q  = (const float*)d_in[0];
    const float* K  = (const float*)d_in[1];
    const float* V  = (const float*)d_in[2];
    // d_in[3] = mask: all ones -> identity (enables linearization)
    const float* Wq = (const float*)d_in[4];
    const float* bq = (const float*)d_in[5];
    const float* Wk = (const float*)d_in[6];
    const float* bk = (const float*)d_in[7];
    const float* Wv = (const float*)d_in[8];
    const float* bv = (const float*)d_in[9];
    const float* Wp = (const float*)d_in[10];
    const float* bp = (const float*)d_in[11];
    float* out = (float*)d_out;

    char* ws = (char*)d_ws;
    float* qkv = (float*)ws;                              // 3*16384*64 fp32 = 12.58 MB
    size_t off = (size_t)3 * T_TOK * HS * sizeof(float);
    short* Xbf = (short*)(ws + off); off += (size_t)1024 * 1024 * 2;   // 2 MB
    short* Wtq = (short*)(ws + off); off += (size_t)HS * KDIM * 2;     // 128 KB
    short* Wtk = (short*)(ws + off); off += (size_t)HS * KDIM * 2;
    short* Wtv = (short*)(ws + off); off += (size_t)HS * KDIM * 2;
    short* Wpt = (short*)(ws + off); off += (size_t)KDIM * KDIM * 2;   // 2 MB

    wtrans_kernel<<<dim3(304), 256, 0, stream>>>(Wq, Wk, Wv, Wp, Wtq, Wtk, Wtv, Wpt);
    qkv_proj_kernel<<<dim3(T_TOK / 64, 3), 256, 0, stream>>>(
        Q, K, V, Wtq, Wtk, Wtv, bq, bk, bv, qkv);
    group_attn_kernel<<<dim3(1024), 256, 0, stream>>>(qkv, Xbf);
    out_proj_kernel<<<dim3(16, 32), 256, 0, stream>>>(Xbf, Wpt, bp, out);
}